// Round 1
// baseline (1085.480 us; speedup 1.0000x reference)
//
#include <hip/hip_runtime.h>
#include <hip/hip_fp16.h>

#define BB 256
#define SS 2048
#define II 128
#define LIN 40
#define HH 20
#define PF 8

// ---------------- Phase 1: gx[b][s][j][4] = (relu(feed@W1^T+b1)@Wih^T + bih + bhh), fp16 ----------------
__global__ __launch_bounds__(256) void k_prep(const float* __restrict__ feed,
    const float* __restrict__ W1, const float* __restrict__ b1,
    const float* __restrict__ Wih, const float* __restrict__ bih,
    const float* __restrict__ bhh, __half* __restrict__ gx)
{
    __shared__ float w1s[40 * 132];    // pad 132: b128-aligned, conflict-free
    __shared__ float wihs[80 * 40];
    __shared__ float b1s[40];
    __shared__ float bs[80];
    __shared__ float ft[64 * 132];     // feed tile; aliased as gxs after GEMM1
    __shared__ float xs[64 * 44];
    unsigned* gxs = (unsigned*)ft;

    const int t = threadIdx.x;
    for (int it = t; it < 40 * 128; it += 256) { int jj = it >> 7, k = it & 127; w1s[jj * 132 + k] = W1[it]; }
    for (int it = t; it < 80 * 40; it += 256) wihs[it] = Wih[it];
    if (t < 40) b1s[t] = b1[t];
    else if (t >= 64 && t < 144) bs[t - 64] = bih[t - 64] + bhh[t - 64];

    const int blk = blockIdx.x;
    const int b = blk >> 5;            // 32 s-tiles of 64 per batch
    const int s0 = (blk & 31) << 6;

    const float4* fsrc = (const float4*)(feed + ((size_t)b * SS + s0) * II);
    for (int it = t; it < 2048; it += 256) {   // 64 rows x 32 float4
        int row = it >> 5, kq = it & 31;
        *(float4*)&ft[row * 132 + kq * 4] = fsrc[it];
    }
    __syncthreads();

    const int r = t >> 2;              // 0..63 row
    const int q = t & 3;               // j-group

    // GEMM1: x[r][j] = relu(feed_row . W1[j] + b1[j]), j = q*10..q*10+9
    float acc[10];
#pragma unroll
    for (int jj = 0; jj < 10; jj++) acc[jj] = b1s[q * 10 + jj];
    const float* arow = &ft[r * 132];
    for (int k4 = 0; k4 < 128; k4 += 4) {
        float4 a = *(const float4*)&arow[k4];
#pragma unroll
        for (int jj = 0; jj < 10; jj++) {
            float4 w = *(const float4*)&w1s[(q * 10 + jj) * 132 + k4];
            acc[jj] = fmaf(a.x, w.x, acc[jj]);
            acc[jj] = fmaf(a.y, w.y, acc[jj]);
            acc[jj] = fmaf(a.z, w.z, acc[jj]);
            acc[jj] = fmaf(a.w, w.w, acc[jj]);
        }
    }
#pragma unroll
    for (int jj = 0; jj < 10; jj++) xs[r * 44 + q * 10 + jj] = fmaxf(acc[jj], 0.f);
    __syncthreads();

    // GEMM2: gates for j = q*5..q*5+4, all 4 gate types (rows T*20+j of Wih)
    float a2[4][5];
#pragma unroll
    for (int T = 0; T < 4; T++)
#pragma unroll
        for (int jj = 0; jj < 5; jj++) a2[T][jj] = bs[T * 20 + q * 5 + jj];
    for (int k4 = 0; k4 < 40; k4 += 4) {
        float4 xv = *(const float4*)&xs[r * 44 + k4];
#pragma unroll
        for (int T = 0; T < 4; T++) {
#pragma unroll
            for (int jj = 0; jj < 5; jj++) {
                float4 w = *(const float4*)&wihs[(T * 20 + q * 5 + jj) * 40 + k4];
                a2[T][jj] = fmaf(xv.x, w.x, a2[T][jj]);
                a2[T][jj] = fmaf(xv.y, w.y, a2[T][jj]);
                a2[T][jj] = fmaf(xv.z, w.z, a2[T][jj]);
                a2[T][jj] = fmaf(xv.w, w.w, a2[T][jj]);
            }
        }
    }
    // pack per-j quads (i,f,g,o) as fp16 into LDS (ft is dead: safe alias)
#pragma unroll
    for (int jj = 0; jj < 5; jj++) {
        int jidx = q * 5 + jj;
        __half2 lo = __floats2half2_rn(a2[0][jj], a2[1][jj]);   // i,f
        __half2 hi2 = __floats2half2_rn(a2[2][jj], a2[3][jj]);  // g,o
        gxs[r * 44 + jidx * 2]     = *(unsigned*)&lo;
        gxs[r * 44 + jidx * 2 + 1] = *(unsigned*)&hi2;
    }
    __syncthreads();
    // coalesced store: 64 rows x 160B
    uint4* gdst = (uint4*)(gx + ((size_t)b * SS + s0) * 80);
    for (int it = t; it < 640; it += 256) {
        int row = it / 10, qq = it - row * 10;
        gdst[row * 10 + qq] = *(uint4*)&gxs[row * 44 + qq * 4];
    }
}

// ---------------- Phase 2: LSTM scan, one wave per batch chain ----------------
__device__ __forceinline__ float bcast(float v, int k) {
    return __uint_as_float(__builtin_amdgcn_readlane(__float_as_uint(v), k));
}

__global__ __launch_bounds__(64) void k_scan(const __half* __restrict__ gx,
    const float* __restrict__ Whh, const float* __restrict__ h0,
    const float* __restrict__ c0, float* __restrict__ hsum)
{
    const int lane = threadIdx.x;
    const int b = blockIdx.x;
    const bool hi = lane >= 32;
    const int jraw = hi ? (lane - 32) : lane;
    const int j = jraw > 19 ? 19 : jraw;          // clamp idle lanes to safe addrs
    const int r1 = hi ? (40 + j) : j;             // g-row : i-row
    const int r2 = hi ? (60 + j) : (20 + j);      // o-row : f-row
    float w1[20], w2[20];
#pragma unroll
    for (int k = 0; k < 20; k++) { w1[k] = Whh[r1 * 20 + k]; w2[k] = Whh[r2 * 20 + k]; }

    const unsigned* gp = (const unsigned*)gx + ((size_t)b * (SS * 40) + j * 2 + (hi ? 1 : 0));
    unsigned buf[PF];
#pragma unroll
    for (int u = 0; u < PF; u++) buf[u] = gp[u * 40];

    float h = h0[b * 20 + j];
    float cc = c0[b * 20 + j];
    float hs = 0.f;
    const float si = hi ? 2.f : 1.f;   // tanh = 2*sigmoid(2x)-1 on hi lanes' first gate
    const float so = hi ? -1.f : 0.f;

    for (int s0 = 0; s0 < SS; s0 += PF) {
#pragma unroll
        for (int u = 0; u < PF; u++) {
            unsigned gv = buf[u];
            int sn = s0 + u + PF; sn = sn > SS - 1 ? SS - 1 : sn;
            buf[u] = gp[(size_t)sn * 40];
            float2 gf = __half22float2(*(__half2*)&gv);
            float p1 = gf.x, p2 = gf.y;
#pragma unroll
            for (int k = 0; k < 20; k++) {
                float hk = bcast(h, k);
                p1 = fmaf(w1[k], hk, p1);
                p2 = fmaf(w2[k], hk, p2);
            }
            float e1 = __builtin_amdgcn_rcpf(1.f + __expf(-(p1 * si)));
            float a1 = fmaf(si, e1, so);                      // lo: sigmoid(i) | hi: tanh(g)
            float a2 = __builtin_amdgcn_rcpf(1.f + __expf(-p2)); // lo: sigmoid(f) | hi: sigmoid(o)
            float gg = __shfl_xor(a1, 32, 64);                // lo lanes receive tanh(g)
            float oo = __shfl_xor(a2, 32, 64);                // lo lanes receive sigmoid(o)
            cc = fmaf(a2, cc, a1 * gg);                       // c = f*c + i*g (valid on lanes<20)
            float th = fmaf(2.f, __builtin_amdgcn_rcpf(1.f + __expf(-2.f * cc)), -1.f);
            h = oo * th;                                      // valid on lanes<20
            hs += h;
        }
    }
    if (lane < 20) hsum[b * 20 + lane] = hs;
}

// ---------------- Phase 3: out[b][o] = (hsum[b]/S) . Wf[o] + bf[o] ----------------
__global__ __launch_bounds__(256) void k_out(const float* __restrict__ hsum,
    const float* __restrict__ Wf, const float* __restrict__ bf, float* __restrict__ out)
{
    int b = threadIdx.x;
    float a0 = 0.f, a1 = 0.f;
#pragma unroll
    for (int k = 0; k < 20; k++) {
        float hv = hsum[b * 20 + k];
        a0 = fmaf(hv, Wf[k], a0);
        a1 = fmaf(hv, Wf[20 + k], a1);
    }
    const float inv = 1.f / 2048.f;
    out[b * 2]     = fmaf(a0, inv, bf[0]);
    out[b * 2 + 1] = fmaf(a1, inv, bf[1]);
}

extern "C" void kernel_launch(void* const* d_in, const int* in_sizes, int n_in,
                              void* d_out, int out_size, void* d_ws, size_t ws_size,
                              hipStream_t stream) {
    const float* feed = (const float*)d_in[0];
    const float* W1   = (const float*)d_in[1];
    const float* b1   = (const float*)d_in[2];
    const float* Wih  = (const float*)d_in[3];
    const float* Whh  = (const float*)d_in[4];
    const float* bih  = (const float*)d_in[5];
    const float* bhh  = (const float*)d_in[6];
    const float* Wf   = (const float*)d_in[7];
    const float* bf   = (const float*)d_in[8];
    const float* h0   = (const float*)d_in[9];
    const float* c0   = (const float*)d_in[10];

    __half* gx  = (__half*)d_ws;                                   // 256*2048*80 fp16 = 84 MB
    float* hsum = (float*)((char*)d_ws + (size_t)BB * SS * 80 * 2); // 20 KB
    float* out  = (float*)d_out;

    hipLaunchKernelGGL(k_prep, dim3(BB * (SS / 64)), dim3(256), 0, stream,
                       feed, W1, b1, Wih, bih, bhh, gx);
    hipLaunchKernelGGL(k_scan, dim3(BB), dim3(64), 0, stream, gx, Whh, h0, c0, hsum);
    hipLaunchKernelGGL(k_out, dim3(1), dim3(256), 0, stream, hsum, Wf, bf, out);
}